// Round 2
// baseline (39.278 us; speedup 1.0000x reference)
//
#include <hip/hip_runtime.h>

#define NATOMS 8192
#define NFREE  4096

constexpr int TPB = 256;          // threads per block (4 waves)
constexpr int IPT = 8;            // i-atoms per thread
constexpr int TI  = TPB * IPT;    // 2048 i-atoms per block
constexpr int JT  = 32;           // j-atoms per block
constexpr int GI  = NATOMS / TI;  // 4
constexpr int GJ  = NATOMS / JT;  // 256
constexpr int NVBLK = GI * GJ;    // 1024 pair blocks
constexpr int NTBLK = NFREE / TPB; // 16

__device__ __forceinline__ float wave_reduce(float v) {
#pragma unroll
    for (int off = 32; off > 0; off >>= 1)
        v += __shfl_down(v, off, 64);
    return v;
}

// P[i] = (-2x, -2y, -2z, x^2+y^2+z^2) from x0; also zero the completion counter.
__global__ void build_P(const float* __restrict__ x0, float4* __restrict__ P,
                        int* __restrict__ counter) {
    int i = blockIdx.x * blockDim.x + threadIdx.x;
    if (i == 0) *counter = 0;
    float x = x0[3 * i + 0], y = x0[3 * i + 1], z = x0[3 * i + 2];
    P[i] = make_float4(-2.f * x, -2.f * y, -2.f * z, fmaf(x, x, fmaf(y, y, z * z)));
}

// Overwrite P at free_idx with q-derived rows; per-block partial sums of qd^2.
__global__ void scatter_q(const float* __restrict__ q, const float* __restrict__ qd,
                          const int* __restrict__ free_idx,
                          float4* __restrict__ P, float* __restrict__ tpart) {
    int t = blockIdx.x * blockDim.x + threadIdx.x;
    int i = free_idx[t];
    float x = q[3 * t + 0], y = q[3 * t + 1], z = q[3 * t + 2];
    P[i] = make_float4(-2.f * x, -2.f * y, -2.f * z, fmaf(x, x, fmaf(y, y, z * z)));
    float a = qd[3 * t + 0], b = qd[3 * t + 1], c = qd[3 * t + 2];
    float tq = fmaf(a, a, fmaf(b, b, c * c));
    tq = wave_reduce(tq);
    __shared__ float s[TPB / 64];
    int lane = threadIdx.x & 63, wid = threadIdx.x >> 6;
    if (lane == 0) s[wid] = tq;
    __syncthreads();
    if (threadIdx.x == 0)
        tpart[blockIdx.x] = (s[0] + s[1]) + (s[2] + s[3]);
}

// All-pairs 1/r via r2 = si + sj - 2*xi.xj (pre-scaled j side). Last block finalizes.
__global__ __launch_bounds__(TPB) void pair_kernel(const float4* __restrict__ P,
                                                   const float* __restrict__ tpart,
                                                   float* __restrict__ vpart,
                                                   int* __restrict__ counter,
                                                   float* __restrict__ out) {
    const int i0 = blockIdx.x * TI;
    const int j0 = blockIdx.y * JT;
    const int t  = threadIdx.x;

    float xi[IPT], yi[IPT], zi[IPT], si[IPT], acc[IPT];
#pragma unroll
    for (int k = 0; k < IPT; ++k) {
        float4 p = P[i0 + t + k * TPB];
        xi[k] = -0.5f * p.x;
        yi[k] = -0.5f * p.y;
        zi[k] = -0.5f * p.z;
        si[k] = p.w;
        acc[k] = 0.f;
    }

    const bool diag = (j0 >= i0) && (j0 < i0 + TI);
    if (diag) {
        // j-slab overlaps this block's i-range: mask the i==j term.
        for (int j = 0; j < JT; ++j) {
            float4 pj = P[j0 + j];
            int rel = j0 + j - i0;
#pragma unroll
            for (int k = 0; k < IPT; ++k) {
                float d = fmaf(xi[k], pj.x, si[k]);
                d = fmaf(yi[k], pj.y, d);
                d = fmaf(zi[k], pj.z, d);
                float r2 = d + pj.w;
                float rinv = __builtin_amdgcn_rsqf(fmaxf(r2, 1e-12f));
                acc[k] += (t + k * TPB == rel) ? 0.f : rinv;
            }
        }
    } else {
#pragma unroll 4
        for (int j = 0; j < JT; ++j) {
            float4 pj = P[j0 + j];
#pragma unroll
            for (int k = 0; k < IPT; ++k) {
                float d = fmaf(xi[k], pj.x, si[k]);
                d = fmaf(yi[k], pj.y, d);
                d = fmaf(zi[k], pj.z, d);
                float r2 = d + pj.w;
                acc[k] += __builtin_amdgcn_rsqf(fmaxf(r2, 1e-12f));
            }
        }
    }

    float v = ((acc[0] + acc[1]) + (acc[2] + acc[3])) +
              ((acc[4] + acc[5]) + (acc[6] + acc[7]));
    v = wave_reduce(v);
    __shared__ float s[TPB / 64];
    __shared__ bool sdone;
    int lane = t & 63, wid = t >> 6;
    if (lane == 0) s[wid] = v;
    __syncthreads();
    if (t == 0) {
        vpart[blockIdx.y * GI + blockIdx.x] = (s[0] + s[1]) + (s[2] + s[3]);
        __threadfence();
        int old = atomicAdd(counter, 1);
        sdone = (old == NVBLK - 1);
    }
    __syncthreads();

    if (sdone) {
        // Deterministic final reduction (fixed index order, single block).
        float v2 = 0.f;
        for (int idx = t; idx < NVBLK; idx += TPB)
            v2 += __hip_atomic_load(&vpart[idx], __ATOMIC_RELAXED, __HIP_MEMORY_SCOPE_AGENT);
        v2 = wave_reduce(v2);
        if (lane == 0) s[wid] = v2;
        __syncthreads();
        if (t == 0) {
            float V = (s[0] + s[1]) + (s[2] + s[3]);
            float T = 0.f;
            for (int i = 0; i < NTBLK; ++i) T += tpart[i];
            out[0] = 0.5f * T - V;
        }
    }
}

extern "C" void kernel_launch(void* const* d_in, const int* in_sizes, int n_in,
                              void* d_out, int out_size, void* d_ws, size_t ws_size,
                              hipStream_t stream) {
    const float* q        = (const float*)d_in[0];
    const float* qd       = (const float*)d_in[1];
    const float* x0       = (const float*)d_in[2];
    const int*   free_idx = (const int*)d_in[3];
    float* out = (float*)d_out;

    float4* P     = (float4*)d_ws;
    float*  vpart = (float*)d_ws + 4 * NATOMS;
    float*  tpart = vpart + NVBLK;
    int*    counter = (int*)(tpart + NTBLK);

    build_P<<<NATOMS / TPB, TPB, 0, stream>>>(x0, P, counter);
    scatter_q<<<NTBLK, TPB, 0, stream>>>(q, qd, free_idx, P, tpart);
    pair_kernel<<<dim3(GI, GJ), TPB, 0, stream>>>(P, tpart, vpart, counter, out);
}